// Round 1
// baseline (272.273 us; speedup 1.0000x reference)
//
#include <hip/hip_runtime.h>

#define EMBED 1024
#define HEADS 16
#define HDIM  64
#define BATCH 2
#define SEQ   2048
#define MTOT  (BATCH*SEQ)   // 4096

typedef __attribute__((ext_vector_type(8))) short bf16x8;
typedef __attribute__((ext_vector_type(4))) short bf16x4;
typedef __attribute__((ext_vector_type(4))) float f32x4;
typedef __attribute__((ext_vector_type(8))) unsigned short u16x8;

__device__ __forceinline__ unsigned short f2bf(float f) {
    unsigned u = __builtin_bit_cast(unsigned, f);
    u += 0x7fffu + ((u >> 16) & 1u);
    return (unsigned short)(u >> 16);
}

__device__ __forceinline__ f32x4 mfma16(bf16x4 a, bf16x4 b, f32x4 c) {
#if __has_builtin(__builtin_amdgcn_mfma_f32_16x16x16bf16_1k)
    return __builtin_amdgcn_mfma_f32_16x16x16bf16_1k(a, b, c, 0, 0, 0);
#else
    f32x4 d;
    asm volatile("v_mfma_f32_16x16x16_bf16 %0, %1, %2, %3"
                 : "=v"(d) : "v"(a), "v"(b), "v"(c));
    return d;
#endif
}

// ------------------------------------------------------------------
// Kernel 1: QKV projection.  Y = X @ W^T + b for W in {wq,wk,wv}.
// X [4096,1024] f32 row-major, W [1024,1024] f32 row-major (out-feature rows).
// q,k -> bf16 [B*H, S, D]; v -> bf16 transposed [B*H, D, S].
// 128x128 tile, BK=32, 4 waves (2x2), each wave 64x64 via 4x4 16x16x32 MFMA.
// ------------------------------------------------------------------
__global__ __launch_bounds__(256, 2) void qkv_proj(
    const float* __restrict__ x,
    const float* __restrict__ wq, const float* __restrict__ bq,
    const float* __restrict__ wk, const float* __restrict__ bk,
    const float* __restrict__ wv, const float* __restrict__ bv,
    unsigned short* __restrict__ qo,
    unsigned short* __restrict__ ko,
    unsigned short* __restrict__ vto)
{
    const int which = blockIdx.z;
    const float* __restrict__ w    = (which == 0) ? wq : (which == 1) ? wk : wv;
    const float* __restrict__ bias = (which == 0) ? bq : (which == 1) ? bk : bv;

    const int m0 = blockIdx.x * 128;
    const int n0 = blockIdx.y * 128;

    // +8 bf16 pad (16B) keeps ds_read_b128 16B-aligned and breaks bank conflicts
    __shared__ unsigned short a_lds[128][40];
    __shared__ unsigned short b_lds[128][40];

    const int tid  = threadIdx.x;
    const int lane = tid & 63;
    const int wid  = tid >> 6;
    const int wr   = wid >> 1, wc = wid & 1;
    const int lq   = lane & 15;      // row/col within fragment
    const int lg   = lane >> 4;      // k-group

    f32x4 acc[4][4] = {};

    const int srow = tid >> 2;       // 0..63
    const int scol = (tid & 3) * 8;  // 0,8,16,24

    for (int k0 = 0; k0 < EMBED; k0 += 32) {
        #pragma unroll
        for (int p = 0; p < 2; ++p) {
            const int r = srow + p * 64;
            const float4* sa = (const float4*)(x + (size_t)(m0 + r) * EMBED + k0 + scol);
            float4 a0 = sa[0], a1 = sa[1];
            u16x8 ta;
            ta[0]=f2bf(a0.x); ta[1]=f2bf(a0.y); ta[2]=f2bf(a0.z); ta[3]=f2bf(a0.w);
            ta[4]=f2bf(a1.x); ta[5]=f2bf(a1.y); ta[6]=f2bf(a1.z); ta[7]=f2bf(a1.w);
            *(u16x8*)&a_lds[r][scol] = ta;
            const float4* sb = (const float4*)(w + (size_t)(n0 + r) * EMBED + k0 + scol);
            float4 b0 = sb[0], b1 = sb[1];
            u16x8 tb;
            tb[0]=f2bf(b0.x); tb[1]=f2bf(b0.y); tb[2]=f2bf(b0.z); tb[3]=f2bf(b0.w);
            tb[4]=f2bf(b1.x); tb[5]=f2bf(b1.y); tb[6]=f2bf(b1.z); tb[7]=f2bf(b1.w);
            *(u16x8*)&b_lds[r][scol] = tb;
        }
        __syncthreads();
        bf16x8 af[4], bfr[4];
        #pragma unroll
        for (int i = 0; i < 4; ++i)
            af[i] = *(const bf16x8*)&a_lds[wr*64 + i*16 + lq][lg*8];
        #pragma unroll
        for (int j = 0; j < 4; ++j)
            bfr[j] = *(const bf16x8*)&b_lds[wc*64 + j*16 + lq][lg*8];
        #pragma unroll
        for (int i = 0; i < 4; ++i)
            #pragma unroll
            for (int j = 0; j < 4; ++j)
                acc[i][j] = __builtin_amdgcn_mfma_f32_16x16x32_bf16(af[i], bfr[j], acc[i][j], 0, 0, 0);
        __syncthreads();
    }

    // Epilogue. C/D layout: col = lane&15, row = (lane>>4)*4 + reg.
    #pragma unroll
    for (int j = 0; j < 4; ++j) {
        const int nn = n0 + wc*64 + j*16 + lq;
        const float bsv = bias[nn];
        const int h = nn >> 6, d = nn & (HDIM-1);
        #pragma unroll
        for (int i = 0; i < 4; ++i) {
            const int mmb = m0 + wr*64 + i*16 + lg*4;
            const int b = mmb >> 11;
            const int s = mmb & (SEQ-1);
            const size_t bh = (size_t)(b*HEADS + h);
            if (which == 2) {
                bf16x4 ov;
                #pragma unroll
                for (int r = 0; r < 4; ++r) ov[r] = (short)f2bf(acc[i][j][r] + bsv);
                *(bf16x4*)&vto[(bh*HDIM + d)*SEQ + s] = ov;   // 4 consecutive s
            } else {
                unsigned short* o = (which == 0) ? qo : ko;
                #pragma unroll
                for (int r = 0; r < 4; ++r)
                    o[(bh*SEQ + (s + r))*HDIM + d] = f2bf(acc[i][j][r] + bsv);
            }
        }
    }
}

// ------------------------------------------------------------------
// Kernel 2: flash attention. 1 wave/block, 32 q-rows/block, kv-step 16.
// S^T = mfma(K, Q)  (16x16x32, M=kv, N=q, K=d) -> lane holds 4 kv for q=lane&15
// softmax state per lane (q = lane&15); reduce via shfl_xor 16/32.
// ctx^T = mfma(V^T, P^T) (16x16x16) -> output also column q=lane&15: no shuffles.
// ------------------------------------------------------------------
__global__ __launch_bounds__(64, 2) void attn(
    const unsigned short* __restrict__ q,
    const unsigned short* __restrict__ k,
    const unsigned short* __restrict__ vt,
    unsigned short* __restrict__ ctx)
{
    const int bh = blockIdx.y;
    const int b  = bh >> 4;
    const int h  = bh & (HEADS-1);
    const int q0 = blockIdx.x * 32;
    const int lane = threadIdx.x;
    const int lq = lane & 15, lg = lane >> 4;

    const unsigned short* qb = q  + (size_t)bh * SEQ * HDIM;
    const unsigned short* kb = k  + (size_t)bh * SEQ * HDIM;
    const unsigned short* vb = vt + (size_t)bh * HDIM * SEQ;

    bf16x8 qf[2][2];
    #pragma unroll
    for (int t = 0; t < 2; ++t)
        #pragma unroll
        for (int ks = 0; ks < 2; ++ks)
            qf[t][ks] = *(const bf16x8*)(qb + (size_t)(q0 + t*16 + lq) * HDIM + ks*32 + lg*8);

    f32x4 o[2][4] = {};
    float mrun[2] = {-1e30f, -1e30f};
    float lrun[2] = {0.f, 0.f};
    const float L2E = 1.44269504f;

    for (int kv0 = 0; kv0 < SEQ; kv0 += 16) {
        const bf16x8 kf0 = *(const bf16x8*)(kb + (size_t)(kv0 + lq) * HDIM + lg*8);
        const bf16x8 kf1 = *(const bf16x8*)(kb + (size_t)(kv0 + lq) * HDIM + 32 + lg*8);
        bf16x4 vf[4];
        #pragma unroll
        for (int i = 0; i < 4; ++i)
            vf[i] = *(const bf16x4*)(vb + (size_t)(i*16 + lq) * SEQ + kv0 + lg*4);

        #pragma unroll
        for (int t = 0; t < 2; ++t) {
            f32x4 s = {};
            s = __builtin_amdgcn_mfma_f32_16x16x32_bf16(kf0, qf[t][0], s, 0, 0, 0);
            s = __builtin_amdgcn_mfma_f32_16x16x32_bf16(kf1, qf[t][1], s, 0, 0, 0);
            const float s0 = s[0]*0.125f, s1 = s[1]*0.125f, s2 = s[2]*0.125f, s3 = s[3]*0.125f;
            float tm = fmaxf(fmaxf(s0, s1), fmaxf(s2, s3));
            tm = fmaxf(tm, __shfl_xor(tm, 16));
            tm = fmaxf(tm, __shfl_xor(tm, 32));
            const float mnew = fmaxf(mrun[t], tm);
            const float corr = exp2f((mrun[t] - mnew) * L2E);
            mrun[t] = mnew;
            const float p0 = exp2f((s0 - mnew) * L2E);
            const float p1 = exp2f((s1 - mnew) * L2E);
            const float p2 = exp2f((s2 - mnew) * L2E);
            const float p3 = exp2f((s3 - mnew) * L2E);
            lrun[t] = lrun[t]*corr + ((p0 + p1) + (p2 + p3));
            #pragma unroll
            for (int i = 0; i < 4; ++i) {
                o[t][i][0] *= corr; o[t][i][1] *= corr;
                o[t][i][2] *= corr; o[t][i][3] *= corr;
            }
            bf16x4 pf;
            pf[0] = (short)f2bf(p0); pf[1] = (short)f2bf(p1);
            pf[2] = (short)f2bf(p2); pf[3] = (short)f2bf(p3);
            #pragma unroll
            for (int i = 0; i < 4; ++i)
                o[t][i] = mfma16(vf[i], pf, o[t][i]);
        }
    }

    #pragma unroll
    for (int t = 0; t < 2; ++t) {
        float l2 = lrun[t] + __shfl_xor(lrun[t], 16);
        l2 += __shfl_xor(l2, 32);
        const float inv = 1.0f / l2;
        unsigned short* cb = ctx + ((size_t)(b*SEQ + q0 + t*16 + lq)) * EMBED + h*HDIM;
        #pragma unroll
        for (int i = 0; i < 4; ++i) {
            bf16x4 ov;
            #pragma unroll
            for (int r = 0; r < 4; ++r) ov[r] = (short)f2bf(o[t][i][r] * inv);
            *(bf16x4*)(cb + i*16 + lg*4) = ov;  // d = 16*i + 4*lg + r
        }
    }
}

// ------------------------------------------------------------------
// Kernel 3: output projection. out = ctx @ wo^T + bo, fp32 out.
// ------------------------------------------------------------------
__global__ __launch_bounds__(256, 2) void out_proj(
    const unsigned short* __restrict__ ctx,
    const float* __restrict__ wo, const float* __restrict__ bo,
    float* __restrict__ out)
{
    const int m0 = blockIdx.x * 128;
    const int n0 = blockIdx.y * 128;

    __shared__ unsigned short a_lds[128][40];
    __shared__ unsigned short b_lds[128][40];

    const int tid  = threadIdx.x;
    const int lane = tid & 63;
    const int wid  = tid >> 6;
    const int wr   = wid >> 1, wc = wid & 1;
    const int lq   = lane & 15;
    const int lg   = lane >> 4;

    f32x4 acc[4][4] = {};

    const int srow = tid >> 2;
    const int scol = (tid & 3) * 8;

    for (int k0 = 0; k0 < EMBED; k0 += 32) {
        #pragma unroll
        for (int p = 0; p < 2; ++p) {
            const int r = srow + p * 64;
            *(u16x8*)&a_lds[r][scol] =
                *(const u16x8*)(ctx + (size_t)(m0 + r) * EMBED + k0 + scol);
            const float4* sb = (const float4*)(wo + (size_t)(n0 + r) * EMBED + k0 + scol);
            float4 b0 = sb[0], b1 = sb[1];
            u16x8 tb;
            tb[0]=f2bf(b0.x); tb[1]=f2bf(b0.y); tb[2]=f2bf(b0.z); tb[3]=f2bf(b0.w);
            tb[4]=f2bf(b1.x); tb[5]=f2bf(b1.y); tb[6]=f2bf(b1.z); tb[7]=f2bf(b1.w);
            *(u16x8*)&b_lds[r][scol] = tb;
        }
        __syncthreads();
        bf16x8 af[4], bfr[4];
        #pragma unroll
        for (int i = 0; i < 4; ++i)
            af[i] = *(const bf16x8*)&a_lds[wr*64 + i*16 + lq][lg*8];
        #pragma unroll
        for (int j = 0; j < 4; ++j)
            bfr[j] = *(const bf16x8*)&b_lds[wc*64 + j*16 + lq][lg*8];
        #pragma unroll
        for (int i = 0; i < 4; ++i)
            #pragma unroll
            for (int j = 0; j < 4; ++j)
                acc[i][j] = __builtin_amdgcn_mfma_f32_16x16x32_bf16(af[i], bfr[j], acc[i][j], 0, 0, 0);
        __syncthreads();
    }

    #pragma unroll
    for (int j = 0; j < 4; ++j) {
        const int nn = n0 + wc*64 + j*16 + lq;
        const float bsv = bo[nn];
        #pragma unroll
        for (int i = 0; i < 4; ++i) {
            const int mm = m0 + wr*64 + i*16 + lg*4;
            #pragma unroll
            for (int r = 0; r < 4; ++r)
                out[(size_t)(mm + r) * EMBED + nn] = acc[i][j][r] + bsv;
        }
    }
}

extern "C" void kernel_launch(void* const* d_in, const int* in_sizes, int n_in,
                              void* d_out, int out_size, void* d_ws, size_t ws_size,
                              hipStream_t stream) {
    const float* x  = (const float*)d_in[0];
    const float* wq = (const float*)d_in[1];
    const float* bq = (const float*)d_in[2];
    const float* wk = (const float*)d_in[3];
    const float* bk = (const float*)d_in[4];
    const float* wv = (const float*)d_in[5];
    const float* bv = (const float*)d_in[6];
    const float* wo = (const float*)d_in[7];
    const float* bo = (const float*)d_in[8];
    float* out = (float*)d_out;

    const size_t NELEM = (size_t)MTOT * EMBED;   // 4M elements
    unsigned short* q_ws   = (unsigned short*)d_ws;
    unsigned short* k_ws   = q_ws  + NELEM;
    unsigned short* vt_ws  = k_ws  + NELEM;
    unsigned short* ctx_ws = vt_ws + NELEM;      // total 32 MB bf16

    qkv_proj<<<dim3(MTOT/128, EMBED/128, 3), 256, 0, stream>>>(
        x, wq, bq, wk, bk, wv, bv, q_ws, k_ws, vt_ws);
    attn<<<dim3(SEQ/32, BATCH*HEADS), 64, 0, stream>>>(q_ws, k_ws, vt_ws, ctx_ws);
    out_proj<<<dim3(MTOT/128, EMBED/128), 256, 0, stream>>>(ctx_ws, wo, bo, out);
}